// Round 6
// baseline (15573.715 us; speedup 1.0000x reference)
//
#include <hip/hip_runtime.h>
#include <math.h>

typedef unsigned int u32;
typedef unsigned long long u64;

#define BATCH 64
#define A_TOT 8649
#define TOPN  6000
#define POST  1500
#define NB    4096
#define NT    512
#define KEY_STRIDE 8704
#define RSPACE 6016          // 94 k-words * 64 lanes of rank space

// dynamic LDS layout (bytes):
//   boxes  float4[6016]  @ 0       (96256)
//   areas  float [6016]  @ 96256   (24064)
//   pickrank u32 [1500]  @ 120320  (6000)
//   pend   u32           @ 126320
#define OFF_AREAS  96256
#define OFF_PICK   120320
#define OFF_PEND   126320
#define DYN_LDS    126336

// ---- DPP full-wave min: result valid in lane 63 (proven R2-R4) ----
__device__ __forceinline__ int wave_min_dpp(int v) {
    int t;
    t = __builtin_amdgcn_update_dpp(v, v, 0x111, 0xf, 0xf, false); v = min(v, t); // row_shr:1
    t = __builtin_amdgcn_update_dpp(v, v, 0x112, 0xf, 0xf, false); v = min(v, t); // row_shr:2
    t = __builtin_amdgcn_update_dpp(v, v, 0x114, 0xf, 0xe, false); v = min(v, t); // row_shr:4
    t = __builtin_amdgcn_update_dpp(v, v, 0x118, 0xf, 0xc, false); v = min(v, t); // row_shr:8
    t = __builtin_amdgcn_update_dpp(v, v, 0x142, 0xa, 0xf, false); v = min(v, t); // row_bcast:15
    t = __builtin_amdgcn_update_dpp(v, v, 0x143, 0xc, 0xf, false); v = min(v, t); // row_bcast:31
    return v;
}

// R1-R5 post-mortem: EVERY multi-wave barrier-per-pick structure costs ~2 us
// per pick regardless of body (R1 16-wave/spill 2.0, R5 8-wave/lean 2.4).
// R6 deletes the structure: ONE WAVE runs the whole greedy scan, barrier-free.
// Per-lane bitmask in 2 VGPRs: bit k of lane ln <-> rank (k<<6)|ln, so the
// next pick is just wave_min((ctz<<6)|ln). areas[] read at (k<<6)|ln hits
// bank ln&31 -> 2 lanes/bank, conflict-free (m136).
__global__ __launch_bounds__(NT) void roibbox_kernel(
    const float* __restrict__ deltas,    // [B, A, 4]
    const float* __restrict__ probs,     // [B, A]
    const float* __restrict__ anchors,   // [A, 4]
    float* __restrict__ out,             // [B*POST*4] boxes then [B*POST] scores
    u64*   __restrict__ wskeys)          // [B, KEY_STRIDE]
{
    #pragma clang fp contract(off)
    extern __shared__ __align__(16) char pool[];
    float4* boxes    = (float4*)pool;                  // [RSPACE] rank-indexed
    float*  areas    = (float*)(pool + OFF_AREAS);     // [RSPACE]
    u32*    pickrank = (u32*)(pool + OFF_PICK);        // [POST]
    u32*    pendsh   = (u32*)(pool + OFF_PEND);
    // overlay (dead after sort): buckets + scan temp (36864 B < boxes region)
    u32* bucketA = (u32*)pool;
    u32* bucketB = bucketA + NB;
    u32* stemp   = bucketB + NB;                       // [2*NT]

    const int tid = threadIdx.x;
    const int b   = blockIdx.x;
    const int wv  = tid >> 6;
    const int ln  = tid & 63;
    const float* pb = probs + (size_t)b * A_TOT;
    u64* keys = wskeys + (size_t)b * KEY_STRIDE;

    // ================= Phase A: stable descending score sort =================
    // key = score_bits<<32 | ~idx  -> exact lax.top_k tie semantics
    for (int i = tid; i < NB; i += NT) bucketA[i] = 0u;
    __syncthreads();
    for (int j = tid; j < A_TOT; j += NT) {
        float s = pb[j];
        int bkt = (int)(s * (float)NB);
        bkt = (NB-1) - min(max(bkt, 0), NB-1);
        atomicAdd(&bucketA[bkt], 1u);
    }
    __syncthreads();
    {   // exclusive scan, 8 counts/thread + Hillis-Steele over 512
        int base = tid << 3;
        u32 c[8]; u32 mysum = 0;
        #pragma unroll
        for (int i = 0; i < 8; ++i) { c[i] = bucketA[base+i]; mysum += c[i]; }
        stemp[tid] = mysum;
        __syncthreads();
        int src = 0;
        for (int off = 1; off < NT; off <<= 1) {
            u32 v = stemp[src*NT + tid];
            if (tid >= off) v += stemp[src*NT + tid - off];
            stemp[(src^1)*NT + tid] = v;
            __syncthreads();
            src ^= 1;
        }
        u32 run = stemp[src*NT + tid] - mysum;
        #pragma unroll
        for (int i = 0; i < 8; ++i) { bucketA[base+i] = run; bucketB[base+i] = run; run += c[i]; }
    }
    __syncthreads();
    for (int j = tid; j < A_TOT; j += NT) {
        float s = pb[j];
        int bkt = (int)(s * (float)NB);
        bkt = (NB-1) - min(max(bkt, 0), NB-1);
        u32 pos = atomicAdd(&bucketB[bkt], 1u);
        keys[pos] = ((u64)__float_as_uint(s) << 32) | (u64)(~(u32)j);
    }
    __syncthreads();
    for (int bkt = tid; bkt < NB; bkt += NT) {   // per-bucket insertion sort
        int begin = (int)bucketA[bkt], end = (int)bucketB[bkt];
        for (int k = begin + 1; k < end; ++k) {
            u64 key = keys[k];
            int m = k - 1;
            while (m >= begin && keys[m] < key) { keys[m+1] = keys[m]; --m; }
            keys[m+1] = key;
        }
    }
    __syncthreads();   // buckets dead; LDS becomes the box/area store

    // ====== Phase B: decode top-6000 into LDS (rank-indexed) ======
    for (int i = 0; i < 12; ++i) {
        int r = tid + i*NT;
        if (r < TOPN) {
            u64 kk = keys[r];
            u32 aidx = ~((u32)kk);
            float4 av = *(const float4*)(anchors + (size_t)aidx*4);
            float4 dv = *(const float4*)(deltas + ((size_t)b*A_TOT + aidx)*4);
            float d0 = dv.x*0.1f, d1 = dv.y*0.1f, d2 = dv.z*0.2f, d3 = dv.w*0.2f;
            float ah = av.z - av.x, aw = av.w - av.y;
            float acy = av.x + 0.5f*ah, acx = av.y + 0.5f*aw;
            float h  = (float)exp((double)d2) * ah;   // correctly-rounded fp32 exp
            float w_ = (float)exp((double)d3) * aw;
            float cy = d0*ah + acy;
            float cx = d1*aw + acx;
            float y1 = cy - 0.5f*h, x1 = cx - 0.5f*w_;
            float y2 = cy + 0.5f*h, x2 = cx + 0.5f*w_;
            boxes[r] = make_float4(y1, x1, y2, x2);
            areas[r] = (y2 - y1) * (x2 - x1);          // == reference area_b
        }
    }
    __syncthreads();

    // ====== Phase C: single-wave greedy NMS (no barriers, no argmin LDS) ======
    if (wv == 0) {
        // bit k of act0 <-> rank (k<<6)|ln, k in [0,64); act1: k in [64,94)
        u64 act0 = ~0ull;                                   // ranks <= 4095
        u64 act1 = (ln < 48) ? 0x3FFFFFFFull : 0x1FFFFFFFull; // cap rank < 6000
        u32 pend = POST;
        for (int p = 0; p < POST; ++p) {
            int kl;
            if (act0)      kl = __builtin_ctzll(act0);
            else if (act1) kl = 64 + __builtin_ctzll(act1);
            else           kl = 127;
            u32 v = ((u32)kl << 6) | (u32)ln;               // == my first rank
            u32 rpick = (u32)__builtin_amdgcn_readlane(wave_min_dpp((int)v), 63);
            if (rpick >= TOPN) { pend = (u32)p; break; }
            if (v == rpick) {                               // unique owner clears
                if (kl < 64) act0 &= ~(1ull << kl);
                else         act1 &= ~(1ull << (kl - 64));
            }
            if (ln == 0) pickrank[p] = rpick;
            float4 sb = boxes[rpick];                       // uniform broadcast
            float sy1 = sb.x, sx1 = sb.y, sy2 = sb.z, sx2 = sb.w;
            float sA  = (sy2 - sy1) * (sx2 - sx1);          // == reference area_s
            // area gate: iou <= min(A)/max(A); margins can't flip a ref decision
            float loA = 0.699f  * sA;
            float hiA = 1.4307f * sA;
            u64 m = act0;
            while (m) {
                int k = __builtin_ctzll(m); m &= m - 1;
                int r = (k << 6) | ln;
                float a = areas[r];
                if (a >= loA && a <= hiA) {
                    float4 bx = boxes[r];
                    float yy1 = fmaxf(sy1, bx.x);
                    float xx1 = fmaxf(sx1, bx.y);
                    float yy2 = fminf(sy2, bx.z);
                    float xx2 = fminf(sx2, bx.w);
                    float iy = fmaxf(yy2 - yy1, 0.0f);
                    float ix = fmaxf(xx2 - xx1, 0.0f);
                    float inter = iy * ix;
                    float den = ((sA + a) - inter) + 1e-9f; // exact ref order
                    bool sup;
                    if      (inter > 0.7002f * den) sup = true;
                    else if (inter < 0.6998f * den) sup = false;
                    else sup = (inter / den > 0.7f);        // exact, rare
                    if (sup) act0 &= ~(1ull << k);
                }
            }
            m = act1;
            while (m) {
                int k = __builtin_ctzll(m); m &= m - 1;
                int r = ((k + 64) << 6) | ln;
                float a = areas[r];
                if (a >= loA && a <= hiA) {
                    float4 bx = boxes[r];
                    float yy1 = fmaxf(sy1, bx.x);
                    float xx1 = fmaxf(sx1, bx.y);
                    float yy2 = fminf(sy2, bx.z);
                    float xx2 = fminf(sx2, bx.w);
                    float iy = fmaxf(yy2 - yy1, 0.0f);
                    float ix = fmaxf(xx2 - xx1, 0.0f);
                    float inter = iy * ix;
                    float den = ((sA + a) - inter) + 1e-9f;
                    bool sup;
                    if      (inter > 0.7002f * den) sup = true;
                    else if (inter < 0.6998f * den) sup = false;
                    else sup = (inter / den > 0.7f);
                    if (sup) act1 &= ~(1ull << k);
                }
            }
        }
        if (ln == 0) pendsh[0] = pend;
    }
    __syncthreads();

    // ====== epilogue: parallel coalesced output ======
    const int pend = (int)pendsh[0];
    const size_t sbase = (size_t)BATCH * POST * 4;
    float4* out4 = (float4*)out;
    for (int p = tid; p < POST; p += NT) {
        size_t row = (size_t)b * POST + p;
        if (p < pend) {
            u32 r = pickrank[p];
            float4 bx = boxes[r];
            float4 ob;
            ob.x = fminf(fmaxf(bx.x, 0.f), 1.f);
            ob.y = fminf(fmaxf(bx.y, 0.f), 1.f);
            ob.z = fminf(fmaxf(bx.z, 0.f), 1.f);
            ob.w = fminf(fmaxf(bx.w, 0.f), 1.f);
            out4[row] = ob;
            out[sbase + row] = __uint_as_float((u32)(keys[r] >> 32));
        } else {
            out4[row] = make_float4(0.f, 0.f, 0.f, 0.f);
            out[sbase + row] = 0.f;
        }
    }
}

extern "C" void kernel_launch(void* const* d_in, const int* in_sizes, int n_in,
                              void* d_out, int out_size, void* d_ws, size_t ws_size,
                              hipStream_t stream) {
    const float* deltas  = (const float*)d_in[0];  // [64,31,31,36] f32
    const float* probs   = (const float*)d_in[1];  // [64,31,31,9]  f32
    // d_in[2] = gt_labels (unused)
    const float* anchors = (const float*)d_in[3];  // [8649,4] f32
    float* out = (float*)d_out;                    // 480000 f32
    u64* wskeys = (u64*)d_ws;                      // 64*8704*8 = 4.46 MB

    // opt-in to >64 KB dynamic LDS (gfx950: 160 KB/CU); host attr, capture-safe
    (void)hipFuncSetAttribute((const void*)roibbox_kernel,
                              hipFuncAttributeMaxDynamicSharedMemorySize, DYN_LDS);

    roibbox_kernel<<<dim3(BATCH), dim3(NT), DYN_LDS, stream>>>(
        deltas, probs, anchors, out, wskeys);
}